// Round 10
// baseline (1568.996 us; speedup 1.0000x reference)
//
#include <hip/hip_runtime.h>

typedef __bf16 bf16x4 __attribute__((ext_vector_type(4)));
typedef __bf16 bf16x8 __attribute__((ext_vector_type(8)));
typedef float f32x4 __attribute__((ext_vector_type(4)));
typedef int int4v __attribute__((ext_vector_type(4)));

#define C1SM  0.18033688011112042592f   /* 0.125 * log2(e) */

typedef const __attribute__((address_space(1))) void gvoid_t;
typedef __attribute__((address_space(3))) void lvoid_t;

// ---------------------------------------------------------------- converts

__global__ void cvt_f32_bf16(const float* __restrict__ src, __bf16* __restrict__ dst, int n4)
{
    int i = blockIdx.x * blockDim.x + threadIdx.x;
    if (i >= n4) return;
    f32x4 v = *reinterpret_cast<const f32x4*>(src + (size_t)i * 4);
    bf16x4 o;
    #pragma unroll
    for (int k = 0; k < 4; ++k) o[k] = (__bf16)v[k];
    *reinterpret_cast<bf16x4*>(dst + (size_t)i * 4) = o;
}

// src (nmat, R, C) -> dst (nmat, C, R), bf16
__global__ void transpose_cvt(const float* __restrict__ src, __bf16* __restrict__ dst, int R, int C)
{
    int m = blockIdx.y;
    int n = R * C;
    int i = blockIdx.x * 256 + threadIdx.x;
    if (i >= n) return;
    int c = i / R, r = i - c * R;
    dst[(size_t)m * n + i] = (__bf16)src[(size_t)m * n + (size_t)r * C + c];
}

// src (nmat, R, C) -> dst (nmat, C, R), f32
__global__ void transpose_f32(const float* __restrict__ src, float* __restrict__ dst, int R, int C)
{
    int m = blockIdx.y;
    int n = R * C;
    int i = blockIdx.x * 256 + threadIdx.x;
    if (i >= n) return;
    int c = i / R, r = i - c * R;
    dst[(size_t)m * n + i] = src[(size_t)m * n + (size_t)r * C + c];
}

// ---------------------------------------------------------------- GEMM
// C[z][m][n] = sum_k A[.][m][k0+k] * B[.][n][k0+k] + bias[.][n]   (B^T layout)
// 128x128 tile, BK=32, dbuf global_load_lds staging, coalesced epilogue,
// XCD swizzle. LDS chunk-swizzle keyed on row bits 1-2 ((r>>1)&3): bank =
// (16*(r&1) + 4*chunk)%32 -> each (parity,chunk) pair gets exactly 2 lanes
// = free 2-way aliasing (was 4-way with (r&3) keying).
__global__ __launch_bounds__(256, 5)
void gemm_bt(const __bf16* __restrict__ A, size_t strideA,
             const __bf16* __restrict__ B, size_t strideB,
             const float* __restrict__ bias, int strideBias,
             float* Cf, __bf16* Cb, size_t strideC,
             const int* __restrict__ gidx, int ldk, int Klen,
             size_t splitStride, int ldc, int relu, __bf16* __restrict__ vt)
{
    __shared__ __align__(16) char smem[32768];
    __bf16* lCb = (__bf16*)smem;
    float*  lCf = (float*)smem;

    const int z = blockIdx.z;
    const int g = gidx ? gidx[z] : 0;
    const __bf16* Ab = A + (splitStride ? (size_t)z * Klen : (size_t)z * strideA);
    const __bf16* Bb = B + (splitStride ? (size_t)z * Klen : (size_t)g * strideB);
    __bf16* CbO = Cb ? (Cb + (size_t)z * (splitStride ? splitStride : strideC)) : nullptr;
    float*  CfO = Cf ? (Cf + (size_t)z * strideC) : nullptr;
    const float* biasb = (bias && (!splitStride || z == 0)) ? bias + (size_t)g * strideBias : nullptr;

    const int nx = gridDim.x;
    const int nwg = nx * gridDim.y;
    int orig = blockIdx.y * nx + blockIdx.x;
    int wg = ((nwg & 7) == 0) ? ((orig & 7) * (nwg >> 3) + (orig >> 3)) : orig;
    const int bm = (wg / nx) * 128, bn = (wg % nx) * 128;

    const int t = threadIdx.x;
    const int w = t >> 6, lane = t & 63;
    const int wr = (w >> 1) * 64, wc = (w & 1) * 64;
    const int l16 = lane & 15, lk = lane >> 4;

    // staging: lane -> (row srow, 16B chunk); source chunk XOR by (srow>>1)&3
    const int srow = lane >> 2;
    const int schunk = (lane & 3) ^ ((srow >> 1) & 3);
    // fragment-read chunk (same involution)
    const int ca = (lk ^ ((l16 >> 1) & 3)) * 8;

    f32x4 acc[4][4] = {};

    auto stage = [&](int buf, int kt) {
        __bf16* la = (__bf16*)(smem + buf * 16384);
        __bf16* lb = la + 4096;
        #pragma unroll
        for (int jj = 0; jj < 2; ++jj) {
            const __bf16* ga = Ab + (size_t)(bm + w * 32 + jj * 16 + srow) * ldk + kt + schunk * 8;
            __builtin_amdgcn_global_load_lds((gvoid_t*)ga, (lvoid_t*)&la[(w * 32 + jj * 16) * 32], 16, 0, 0);
            const __bf16* gb = Bb + (size_t)(bn + w * 32 + jj * 16 + srow) * ldk + kt + schunk * 8;
            __builtin_amdgcn_global_load_lds((gvoid_t*)gb, (lvoid_t*)&lb[(w * 32 + jj * 16) * 32], 16, 0, 0);
        }
    };

    stage(0, 0);
    __syncthreads();
    int cur = 0;
    for (int kt = 0; kt < Klen; kt += 32) {
        if (kt + 32 < Klen) stage(cur ^ 1, kt + 32);
        __bf16* la = (__bf16*)(smem + cur * 16384);
        __bf16* lb = la + 4096;
        bf16x8 af[4], bfr[4];
        #pragma unroll
        for (int i = 0; i < 4; ++i) {
            af[i]  = *reinterpret_cast<const bf16x8*>(&la[(wr + i * 16 + l16) * 32 + ca]);
            bfr[i] = *reinterpret_cast<const bf16x8*>(&lb[(wc + i * 16 + l16) * 32 + ca]);
        }
        #pragma unroll
        for (int mi = 0; mi < 4; ++mi)
            #pragma unroll
            for (int ni = 0; ni < 4; ++ni)
                acc[mi][ni] = __builtin_amdgcn_mfma_f32_16x16x32_bf16(af[mi], bfr[ni], acc[mi][ni], 0, 0, 0);
        __syncthreads();
        cur ^= 1;
    }

    if (vt && bn >= 1024) {
        // V third of QKV: store transposed into vt[b][h][d][s], 8B stores.
        const int bb = bm >> 9;
        const int s0 = (bm & 511) + wr + lk * 4;
        #pragma unroll
        for (int ni = 0; ni < 4; ++ni) {
            int c = bn + wc + ni * 16 + l16;
            float bv = biasb ? biasb[c] : 0.f;
            int hh = (c - 1024) >> 6, d = c & 63;
            __bf16* vrow = vt + ((size_t)(bb * 8 + hh) * 64 + d) * 512;
            #pragma unroll
            for (int mi = 0; mi < 4; ++mi) {
                bf16x4 o;
                #pragma unroll
                for (int j = 0; j < 4; ++j) o[j] = (__bf16)(acc[mi][ni][j] + bv);
                *reinterpret_cast<bf16x4*>(vrow + s0 + mi * 16) = o;
            }
        }
        return;
    }

    if (CbO) {
        #pragma unroll
        for (int ni = 0; ni < 4; ++ni) {
            int col = wc + ni * 16 + l16;
            float bv = biasb ? biasb[bn + col] : 0.f;
            #pragma unroll
            for (int mi = 0; mi < 4; ++mi)
                #pragma unroll
                for (int j = 0; j < 4; ++j) {
                    float v = acc[mi][ni][j] + bv;
                    if (relu) v = fmaxf(v, 0.f);
                    lCb[(wr + mi * 16 + lk * 4 + j) * 128 + col] = (__bf16)v;
                }
        }
        __syncthreads();
        #pragma unroll
        for (int it = 0; it < 8; ++it) {
            int off = it * 2048 + t * 8;
            int rl = off >> 7, col = off & 127;
            *reinterpret_cast<int4v*>(CbO + (size_t)(bm + rl) * ldc + bn + col) =
                *reinterpret_cast<const int4v*>(&lCb[off]);
        }
    } else {
        #pragma unroll
        for (int p = 0; p < 2; ++p) {
            if (p) __syncthreads();
            if (wr == p * 64) {
                #pragma unroll
                for (int ni = 0; ni < 4; ++ni) {
                    int col = wc + ni * 16 + l16;
                    float bv = biasb ? biasb[bn + col] : 0.f;
                    #pragma unroll
                    for (int mi = 0; mi < 4; ++mi)
                        #pragma unroll
                        for (int j = 0; j < 4; ++j) {
                            float v = acc[mi][ni][j] + bv;
                            if (relu) v = fmaxf(v, 0.f);
                            lCf[(mi * 16 + lk * 4 + j) * 128 + col] = v;
                        }
                }
            }
            __syncthreads();
            #pragma unroll
            for (int it = 0; it < 8; ++it) {
                int off = it * 1024 + t * 4;
                int rl = off >> 7, col = off & 127;
                *reinterpret_cast<f32x4*>(CfO + (size_t)(bm + p * 64 + rl) * ldc + bn + col) =
                    *reinterpret_cast<const f32x4*>(&lCf[off]);
            }
        }
    }
}

// ---------------------------------------------------------------- attention
// Variant C (r8 winner): grid (256 bh, 4 qt), 32 q-rows/wave, K and V both
// double-buffer staged in LDS via global_load_lds (pre-swizzled source).
// LDS 22.5KB, natural VGPR 64 < 85 cap -> 6 blocks/CU.
__global__ __launch_bounds__(256, 6)
void attn_fwd_c(const __bf16* __restrict__ qkv, const __bf16* __restrict__ vt,
                const int* __restrict__ mask, __bf16* __restrict__ out)
{
    __shared__ __bf16 lK[2][64 * 64];
    __shared__ __bf16 lV[2][64 * 64];
    __shared__ __bf16 lP[4][16 * 32];
    __shared__ float lM2[512];

    const int bh = blockIdx.x;
    const int b = bh >> 3, h = bh & 7;
    const int q0 = blockIdx.y * 128;
    const int t = threadIdx.x, w = t >> 6, lane = t & 63;
    const int l16 = lane & 15, lk = lane >> 4;

    const __bf16* qbase = qkv + (size_t)b * 512 * 1536 + h * 64;
    const __bf16* kbase = qbase + 512;
    const __bf16* vtb = vt + (size_t)(b * 8 + h) * 64 * 512;

    bf16x8 qfr[2][2];
    #pragma unroll
    for (int qn = 0; qn < 2; ++qn) {
        int row = q0 + w * 32 + qn * 16 + l16;
        #pragma unroll
        for (int kc = 0; kc < 2; ++kc)
            qfr[qn][kc] = *reinterpret_cast<const bf16x8*>(qbase + (size_t)row * 1536 + (kc * 4 + lk) * 8);
    }
    {
        int i0 = t * 2;
        lM2[i0]     = (mask[b * 512 + i0] == 0)     ? -2e9f : 0.f;
        lM2[i0 + 1] = (mask[b * 512 + i0 + 1] == 0) ? -2e9f : 0.f;
    }

    auto stageKV = [&](int buf, int kt) {
        #pragma unroll
        for (int r = 0; r < 2; ++r) {
            int c = r * 256 + w * 64 + lane;
            int row = c >> 3, ch = c & 7;
            const __bf16* ga = kbase + (size_t)(kt + row) * 1536 + ((ch ^ (row & 7)) * 8);
            __builtin_amdgcn_global_load_lds((gvoid_t*)ga,
                (lvoid_t*)(&lK[buf][0] + (r * 256 + w * 64) * 8), 16, 0, 0);
            const __bf16* gv = vtb + (size_t)row * 512 + kt + ((ch ^ (row & 7)) * 8);
            __builtin_amdgcn_global_load_lds((gvoid_t*)gv,
                (lvoid_t*)(&lV[buf][0] + (r * 256 + w * 64) * 8), 16, 0, 0);
        }
    };

    float m_run[2] = {-1e30f, -1e30f}, l_run[2] = {0.f, 0.f};
    f32x4 oacc[2][4] = {};
    const int xsw = ((l16 >> 1) & 3) << 1;

    stageKV(0, 0);
    __syncthreads();

    int cur = 0;
    for (int kt = 0; kt < 512; kt += 64) {
        if (kt + 64 < 512) stageKV(cur ^ 1, kt + 64);
        const __bf16* lKc = &lK[cur][0];
        const __bf16* lVc = &lV[cur][0];
        __bf16* lp = &lP[w][0];

        #pragma unroll
        for (int qn = 0; qn < 2; ++qn) {
            f32x4 sacc[4] = {};
            #pragma unroll
            for (int ni = 0; ni < 4; ++ni) {
                int krow = ni * 16 + l16;
                #pragma unroll
                for (int kc = 0; kc < 2; ++kc) {
                    bf16x8 kf = *reinterpret_cast<const bf16x8*>(&lKc[krow * 64 + (((kc * 4 + lk) ^ (krow & 7)) * 8)]);
                    sacc[ni] = __builtin_amdgcn_mfma_f32_16x16x32_bf16(kf, qfr[qn][kc], sacc[ni], 0, 0, 0);
                }
            }

            f32x4 mx4 = {-3e38f, -3e38f, -3e38f, -3e38f};
            #pragma unroll
            for (int ni = 0; ni < 4; ++ni) {
                f32x4 mkv = *reinterpret_cast<const f32x4*>(&lM2[kt + ni * 16 + lk * 4]);
                f32x4 sv;
                #pragma unroll
                for (int j = 0; j < 4; ++j) {
                    sv[j] = fmaf(sacc[ni][j], C1SM, mkv[j]);
                    mx4[j] = fmaxf(mx4[j], sv[j]);
                }
                sacc[ni] = sv;
            }
            float mx = fmaxf(fmaxf(mx4[0], mx4[1]), fmaxf(mx4[2], mx4[3]));
            mx = fmaxf(mx, __shfl_xor(mx, 16));
            mx = fmaxf(mx, __shfl_xor(mx, 32));
            bool need = mx > m_run[qn] + 11.54f;
            if (__any((int)need)) {
                float mn = fmaxf(m_run[qn], mx);
                float alpha = exp2f(m_run[qn] - mn);
                m_run[qn] = mn;
                l_run[qn] *= alpha;
                #pragma unroll
                for (int j = 0; j < 4; ++j) {
                    float aj = __shfl(alpha, lk * 4 + j);
                    #pragma unroll
                    for (int dn = 0; dn < 4; ++dn) oacc[qn][dn][j] *= aj;
                }
            }
            f32x4 ps4 = {0.f, 0.f, 0.f, 0.f};
            #pragma unroll
            for (int ni = 0; ni < 4; ++ni)
                #pragma unroll
                for (int j = 0; j < 4; ++j) {
                    float p = exp2f(sacc[ni][j] - m_run[qn]);
                    sacc[ni][j] = p;
                    ps4[j] += p;
                }
            l_run[qn] += (ps4[0] + ps4[1]) + (ps4[2] + ps4[3]);

            #pragma unroll
            for (int kc = 0; kc < 2; ++kc) {
                #pragma unroll
                for (int n2 = 0; n2 < 2; ++n2) {
                    bf16x4 o;
                    #pragma unroll
                    for (int j = 0; j < 4; ++j) o[j] = (__bf16)sacc[kc * 2 + n2][j];
                    *reinterpret_cast<bf16x4*>(&lp[l16 * 32 + ((n2 * 4 + lk) ^ xsw) * 4]) = o;
                }
                bf16x8 pf = *reinterpret_cast<const bf16x8*>(&lp[l16 * 32 + (lk ^ (xsw >> 1)) * 8]);
                #pragma unroll
                for (int dn = 0; dn < 4; ++dn) {
                    int vrow = dn * 16 + l16;
                    bf16x8 vf = *reinterpret_cast<const bf16x8*>(&lVc[vrow * 64 + (((kc * 4 + lk) ^ (vrow & 7)) * 8)]);
                    oacc[qn][dn] = __builtin_amdgcn_mfma_f32_16x16x32_bf16(pf, vf, oacc[qn][dn], 0, 0, 0);
                }
            }
        }
        __syncthreads();
        cur ^= 1;
    }

    #pragma unroll
    for (int qn = 0; qn < 2; ++qn) {
        float s = l_run[qn];
        s += __shfl_xor(s, 16);
        s += __shfl_xor(s, 32);
        float linv = 1.f / s;
        #pragma unroll
        for (int j = 0; j < 4; ++j) {
            float lj = __shfl(linv, lk * 4 + j);
            #pragma unroll
            for (int dn = 0; dn < 4; ++dn) {
                int row = q0 + w * 32 + qn * 16 + lk * 4 + j;
                int col = h * 64 + dn * 16 + l16;
                out[(size_t)(b * 512 + row) * 512 + col] = (__bf16)(oacc[qn][dn][j] * lj);
            }
        }
    }
}

// ---------------------------------------------------------------- elementwise

__device__ __forceinline__ float wsum64(float v)
{
    #pragma unroll
    for (int d = 32; d >= 1; d >>= 1) v += __shfl_xor(v, d);
    return v;
}

// x = LN(resid + projA + projB) * gamma + beta; bf16 residual stream, in-place.
__global__ __launch_bounds__(256)
void ln_fuse2(const __bf16* resid, const __bf16* __restrict__ pA,
              const __bf16* __restrict__ pB,
              const float* __restrict__ gamma, const float* __restrict__ beta,
              __bf16* xbo)
{
    int tok = blockIdx.x * 4 + (threadIdx.x >> 6);
    int lane = threadIdx.x & 63;
    size_t base = (size_t)tok * 512 + lane * 8;
    float y[8];
    {
        bf16x8 rv = *reinterpret_cast<const bf16x8*>(resid + base);
        bf16x8 pa = *reinterpret_cast<const bf16x8*>(pA + base);
        bf16x8 pb = *reinterpret_cast<const bf16x8*>(pB + base);
        #pragma unroll
        for (int i = 0; i < 8; ++i) y[i] = (float)rv[i] + (float)pa[i] + (float)pb[i];
    }
    float s = 0.f;
    #pragma unroll
    for (int i = 0; i < 8; ++i) s += y[i];
    float mean = wsum64(s) * (1.f / 512.f);
    float v = 0.f;
    #pragma unroll
    for (int i = 0; i < 8; ++i) { float d = y[i] - mean; v += d * d; }
    float rstd = rsqrtf(wsum64(v) * (1.f / 512.f) + 1e-5f);
    int hh = lane * 8;
    f32x4 g0 = *reinterpret_cast<const f32x4*>(gamma + hh);
    f32x4 g1 = *reinterpret_cast<const f32x4*>(gamma + hh + 4);
    f32x4 b0 = *reinterpret_cast<const f32x4*>(beta + hh);
    f32x4 b1 = *reinterpret_cast<const f32x4*>(beta + hh + 4);
    bf16x8 ob;
    #pragma unroll
    for (int i = 0; i < 4; ++i) {
        ob[i]     = (__bf16)((y[i] - mean) * rstd * g0[i] + b0[i]);
        ob[4 + i] = (__bf16)((y[4 + i] - mean) * rstd * g1[i] + b1[i]);
    }
    *reinterpret_cast<bf16x8*>(xbo + base) = ob;
}

// x = relu(LN(se)*g+b) + act_emb[g,a] + rtg*retW + retb + time_emb[t] + game_emb[g]
__global__ __launch_bounds__(256)
void embed_fin(const __bf16* __restrict__ seraw, const int* __restrict__ gi,
               const int* __restrict__ actions, const float* __restrict__ rtg,
               const int* __restrict__ ts,
               const float* __restrict__ olg, const float* __restrict__ olb,
               const float* __restrict__ act_emb, const float* __restrict__ retW,
               const float* __restrict__ retb, const float* __restrict__ time_emb,
               const float* __restrict__ game_emb,
               __bf16* __restrict__ xbo)
{
    int tok = blockIdx.x * 4 + (threadIdx.x >> 6);
    int lane = threadIdx.x & 63;
    int b = tok >> 9;
    int g = gi[b];
    int a = actions[tok];
    int tt = ts[tok];
    float rv = rtg[tok];
    size_t base = (size_t)tok * 512 + lane * 8;
    int hh = lane * 8;

    float y[8];
    {
        bf16x8 a0 = *reinterpret_cast<const bf16x8*>(seraw + base);
        #pragma unroll
        for (int i = 0; i < 8; ++i) y[i] = (float)a0[i];
    }
    float s = 0.f;
    #pragma unroll
    for (int i = 0; i < 8; ++i) s += y[i];
    float mean = wsum64(s) * (1.f / 512.f);
    float v = 0.f;
    #pragma unroll
    for (int i = 0; i < 8; ++i) { float d = y[i] - mean; v += d * d; }
    float rstd = rsqrtf(wsum64(v) * (1.f / 512.f) + 1e-5f);

    const float* gp = olg + (size_t)g * 512 + hh;
    const float* bp = olb + (size_t)g * 512 + hh;
    const float* ap = act_emb + ((size_t)g * 18 + a) * 512 + hh;
    const float* tp = time_emb + (size_t)tt * 512 + hh;
    const float* ep = game_emb + (size_t)g * 512 + hh;
    const float* rwp = retW + hh;
    const float* rbp = retb + hh;

    bf16x8 ob;
    #pragma unroll
    for (int half = 0; half < 2; ++half) {
        f32x4 gv = *reinterpret_cast<const f32x4*>(gp + half * 4);
        f32x4 bv = *reinterpret_cast<const f32x4*>(bp + half * 4);
        f32x4 av = *reinterpret_cast<const f32x4*>(ap + half * 4);
        f32x4 tv = *reinterpret_cast<const f32x4*>(tp + half * 4);
        f32x4 ev = *reinterpret_cast<const f32x4*>(ep + half * 4);
        f32x4 rw = *reinterpret_cast<const f32x4*>(rwp + half * 4);
        f32x4 rb = *reinterpret_cast<const f32x4*>(rbp + half * 4);
        #pragma unroll
        for (int i = 0; i < 4; ++i) {
            float n = (y[half * 4 + i] - mean) * rstd * gv[i] + bv[i];
            n = fmaxf(n, 0.f);
            float o = n + av[i] + rv * rw[i] + rb[i] + tv[i] + ev[i];
            ob[half * 4 + i] = (__bf16)o;
        }
    }
    *reinterpret_cast<bf16x8*>(xbo + base) = ob;
}

// action (18) + return (1) heads; wave per token, shuffle-reduce dots. bf16 x.
__global__ __launch_bounds__(256)
void head_ar(const __bf16* __restrict__ xbv, const int* __restrict__ gi,
             const float* __restrict__ ahWt, const float* __restrict__ ah_b,
             const float* __restrict__ rhW, const float* __restrict__ rhb,
             float* __restrict__ outA, float* __restrict__ outR)
{
    int tok = blockIdx.x * 4 + (threadIdx.x >> 6);
    int lane = threadIdx.x & 63;
    int b = tok >> 9;
    int g = gi[b];
    size_t base = (size_t)tok * 512 + lane * 8;
    float x[8];
    {
        bf16x8 a0 = *reinterpret_cast<const bf16x8*>(xbv + base);
        #pragma unroll
        for (int i = 0; i < 8; ++i) x[i] = (float)a0[i];
    }
    #pragma unroll 1
    for (int a = 0; a < 18; ++a) {
        const float* wp = ahWt + ((size_t)g * 18 + a) * 512 + lane * 8;
        f32x4 w0 = *reinterpret_cast<const f32x4*>(wp);
        f32x4 w1 = *reinterpret_cast<const f32x4*>(wp + 4);
        float p = 0.f;
        #pragma unroll
        for (int i = 0; i < 4; ++i) { p += x[i] * w0[i]; p += x[4 + i] * w1[i]; }
        p = wsum64(p);
        if (lane == 0) outA[(size_t)tok * 18 + a] = p + ah_b[g * 18 + a];
    }
    {
        const float* wp = rhW + lane * 8;
        f32x4 w0 = *reinterpret_cast<const f32x4*>(wp);
        f32x4 w1 = *reinterpret_cast<const f32x4*>(wp + 4);
        float p = 0.f;
        #pragma unroll
        for (int i = 0; i < 4; ++i) { p += x[i] * w0[i]; p += x[4 + i] * w1[i]; }
        p = wsum64(p);
        if (lane == 0) outR[tok] = p + rhb[0];
    }
}

// ---------------------------------------------------------------- launch

extern "C" void kernel_launch(void* const* d_in, const int* in_sizes, int n_in,
                              void* d_out, int out_size, void* d_ws, size_t ws_size,
                              hipStream_t stream)
{
    (void)in_sizes; (void)n_in; (void)out_size; (void)ws_size;

    const int*   gi       = (const int*)d_in[0];
    const float* states   = (const float*)d_in[1];
    const int*   actions  = (const int*)d_in[2];
    const float* rtg      = (const float*)d_in[3];
    const int*   ts       = (const int*)d_in[4];
    const int*   amask    = (const int*)d_in[5];
    const float* game_emb = (const float*)d_in[6];
    const float* obs_W    = (const float*)d_in[7];
    const float* obs_b    = (const float*)d_in[8];
    const float* obs_ln_g = (const float*)d_in[9];
    const float* obs_ln_b = (const float*)d_in[10];
    const float* act_emb  = (const float*)d_in[11];
    const float* ret_W    = (const float*)d_in[12];
    const float* ret_b    = (const float*)d_in[13];
    const float* time_emb = (const float*)d_in[14];
    const float* Wqkv     = (const float*)d_in[15];
    const float* bqkv     = (const float*)d_in[16];
    const float* Wo       = (const float*)d_in[17];
    const float* bo       = (const float*)d_in[18];
    const float* ln1_g    = (const float*)d_in[19];
    const float* ln1_b    = (const float*)d_in[20];
    const float* W1       = (const float*)d_in[21];
    const float* b1       = (const float*)d_in[22];
    const float* W2       = (const float*)d_in[23];
    const float* b2       = (const float*)d_in[24];
    const float* ln2_g    = (const float*)d_in[25];
    const float* ln2_b    = (const float*)d_in[26];
    const float* sh_W     = (const float*)d_in[27];
    const float* sh_b     = (const float*)d_in[28];
    const float* ah_W     = (const float*)d_in[29];
    const float* ah_b     = (const float*)d_in[30];
    const float* rh_W     = (const float*)d_in[31];
    const float* rh_b     = (const float*)d_in[32];

    char* wsb = (char*)d_ws;
    __bf16* tmp     = (__bf16*)(wsb + 0);                      // 16 MiB (proj partial A)
    __bf16* tmp2    = tmp + 8388608;                           // 16 MiB (proj partial B)
    __bf16* xb      = (__bf16*)(wsb + 33554432);               // 16 MiB bf16 residual stream
    __bf16* vT      = (__bf16*)(wsb + 67108864);               // 16 MiB  [b][h][d][s]
    __bf16* qkvB    = (__bf16*)(wsb + 83886080);               // region R1 (64 MiB): qkv / ff1 / states
    __bf16* ff1B    = qkvB;
    __bf16* statesB = qkvB;
    __bf16* obswB   = (__bf16*)(wsb + 83886080 + 8388608);
    __bf16* attnB   = (__bf16*)(wsb + 150994944);              // 16 MiB
    __bf16* wqkvB   = (__bf16*)(wsb + 167772160);
    __bf16* woB     = (__bf16*)(wsb + 177209344);
    __bf16* w1B     = (__bf16*)(wsb + 180355072);
    __bf16* w2B     = (__bf16*)(wsb + 192937984);
    __bf16* shwB    = (__bf16*)(wsb + 205520896);
    float*  ahwT    = (float*)(wsb + 207618048);

    cvt_f32_bf16<<<4608, 256, 0, stream>>>(Wqkv, wqkvB, 1179648);
    cvt_f32_bf16<<<1536, 256, 0, stream>>>(Wo, woB, 393216);
    cvt_f32_bf16<<<6144, 256, 0, stream>>>(W1, w1B, 1572864);
    cvt_f32_bf16<<<6144, 256, 0, stream>>>(W2, w2B, 1572864);
    cvt_f32_bf16<<<4096, 256, 0, stream>>>(states, statesB, 1048576);
    transpose_cvt<<<dim3(512, 8), 256, 0, stream>>>(obs_W, obswB, 256, 512);
    transpose_cvt<<<dim3(512, 8), 256, 0, stream>>>(sh_W, shwB, 512, 256);
    transpose_f32<<<dim3(36, 8), 256, 0, stream>>>(ah_W, ahwT, 512, 18);

    // embedding: se_raw = states @ obs_W[g] + obs_b[g]  (grouped, z=batch)
    gemm_bt<<<dim3(4, 4, 32), 256, 0, stream>>>(
        statesB, (size_t)512 * 256, obswB, (size_t)512 * 256, obs_b, 512,
        nullptr, tmp, (size_t)512 * 512, gi, 256, 256, 0, 512, 0, nullptr);
    embed_fin<<<4096, 256, 0, stream>>>(tmp, gi, actions, rtg, ts,
        obs_ln_g, obs_ln_b, act_emb, ret_W, ret_b, time_emb, game_emb, xb);

    for (int l = 0; l < 6; ++l) {
        // QKV (V third written transposed into vT)
        gemm_bt<<<dim3(12, 128, 1), 256, 0, stream>>>(
            xb, 0, wqkvB + (size_t)l * 1536 * 512, 0, bqkv + l * 1536, 0,
            nullptr, qkvB, 0, nullptr, 512, 512, 0, 1536, 0, vT);
        // attention
        attn_fwd_c<<<dim3(256, 4, 1), 256, 0, stream>>>(qkvB, vT, amask, attnB);
        // Wo projection, split-K=2 (z = K-half; bias on z=0; partials tmp/tmp2)
        gemm_bt<<<dim3(4, 128, 2), 256, 0, stream>>>(
            attnB, 0, woB + (size_t)l * 512 * 512, 0, bo + l * 512, 0,
            nullptr, tmp, 0, nullptr, 512, 256, 8388608, 512, 0, nullptr);
        ln_fuse2<<<4096, 256, 0, stream>>>(xb, tmp, tmp2, ln1_g + l * 512, ln1_b + l * 512, xb);
        // FF1 (relu, bf16 out)
        gemm_bt<<<dim3(16, 128, 1), 256, 0, stream>>>(
            xb, 0, w1B + (size_t)l * 2048 * 512, 0, b1 + l * 2048, 0,
            nullptr, ff1B, 0, nullptr, 512, 512, 0, 2048, 1, nullptr);
        // FF2, split-K=2
        gemm_bt<<<dim3(4, 128, 2), 256, 0, stream>>>(
            ff1B, 0, w2B + (size_t)l * 512 * 2048, 0, b2 + l * 512, 0,
            nullptr, tmp, 0, nullptr, 2048, 1024, 8388608, 512, 0, nullptr);
        ln_fuse2<<<4096, 256, 0, stream>>>(xb, tmp, tmp2, ln2_g + l * 512, ln2_b + l * 512, xb);
    }

    // state head (grouped, writes d_out[0 : 32*512*256))
    gemm_bt<<<dim3(2, 4, 32), 256, 0, stream>>>(
        xb, (size_t)512 * 512, shwB, (size_t)256 * 512, sh_b, 256,
        (float*)d_out, nullptr, (size_t)512 * 256, gi, 512, 512, 0, 256, 0, nullptr);
    // action + return heads
    head_ar<<<4096, 256, 0, stream>>>(xb, gi, ahwT, ah_b, rh_W, rh_b,
        (float*)d_out + 4194304, (float*)d_out + 4489216);
}

// Round 11
// 1424.931 us; speedup vs baseline: 1.1011x; 1.1011x over previous
//
#include <hip/hip_runtime.h>

typedef __bf16 bf16x4 __attribute__((ext_vector_type(4)));
typedef __bf16 bf16x8 __attribute__((ext_vector_type(8)));
typedef float f32x4 __attribute__((ext_vector_type(4)));
typedef int int4v __attribute__((ext_vector_type(4)));

#define C1SM  0.18033688011112042592f   /* 0.125 * log2(e) */

typedef const __attribute__((address_space(1))) void gvoid_t;
typedef __attribute__((address_space(3))) void lvoid_t;

// ---------------------------------------------------------------- converts

__global__ void cvt_f32_bf16(const float* __restrict__ src, __bf16* __restrict__ dst, int n4)
{
    int i = blockIdx.x * blockDim.x + threadIdx.x;
    if (i >= n4) return;
    f32x4 v = *reinterpret_cast<const f32x4*>(src + (size_t)i * 4);
    bf16x4 o;
    #pragma unroll
    for (int k = 0; k < 4; ++k) o[k] = (__bf16)v[k];
    *reinterpret_cast<bf16x4*>(dst + (size_t)i * 4) = o;
}

// src (nmat, R, C) -> dst (nmat, C, R), bf16
__global__ void transpose_cvt(const float* __restrict__ src, __bf16* __restrict__ dst, int R, int C)
{
    int m = blockIdx.y;
    int n = R * C;
    int i = blockIdx.x * 256 + threadIdx.x;
    if (i >= n) return;
    int c = i / R, r = i - c * R;
    dst[(size_t)m * n + i] = (__bf16)src[(size_t)m * n + (size_t)r * C + c];
}

// src (nmat, R, C) -> dst (nmat, C, R), f32
__global__ void transpose_f32(const float* __restrict__ src, float* __restrict__ dst, int R, int C)
{
    int m = blockIdx.y;
    int n = R * C;
    int i = blockIdx.x * 256 + threadIdx.x;
    if (i >= n) return;
    int c = i / R, r = i - c * R;
    dst[(size_t)m * n + i] = src[(size_t)m * n + (size_t)r * C + c];
}

// ---------------------------------------------------------------- GEMM
// C[z][m][n] = sum_k A[.][m][k0+k] * B[.][n][k0+k] + bias[.][n]   (B^T layout)
// 128x128 tile, BK=32, dbuf global_load_lds staging, coalesced epilogue,
// XCD swizzle. LDS chunk-swizzle keyed on row bits 1-2 ((r>>1)&3) -> free
// 2-way bank aliasing (r10-verified: conflicts 5.24M->1.05M).
// launch_bounds 4 blocks/CU: 5 thrashes L2 panel reuse (r10: FETCH +36%,
// WRITE +26%, dur +17% -- do NOT raise).
__global__ __launch_bounds__(256, 4)
void gemm_bt(const __bf16* __restrict__ A, size_t strideA,
             const __bf16* __restrict__ B, size_t strideB,
             const float* __restrict__ bias, int strideBias,
             float* Cf, __bf16* Cb, size_t strideC,
             const int* __restrict__ gidx, int ldk, int Klen,
             size_t splitStride, int ldc, int relu, __bf16* __restrict__ vt)
{
    __shared__ __align__(16) char smem[32768];
    __bf16* lCb = (__bf16*)smem;
    float*  lCf = (float*)smem;

    const int z = blockIdx.z;
    const int g = gidx ? gidx[z] : 0;
    const __bf16* Ab = A + (splitStride ? (size_t)z * Klen : (size_t)z * strideA);
    const __bf16* Bb = B + (splitStride ? (size_t)z * Klen : (size_t)g * strideB);
    __bf16* CbO = Cb ? (Cb + (size_t)z * (splitStride ? splitStride : strideC)) : nullptr;
    float*  CfO = Cf ? (Cf + (size_t)z * strideC) : nullptr;
    const float* biasb = (bias && (!splitStride || z == 0)) ? bias + (size_t)g * strideBias : nullptr;

    const int nx = gridDim.x;
    const int nwg = nx * gridDim.y;
    int orig = blockIdx.y * nx + blockIdx.x;
    int wg = ((nwg & 7) == 0) ? ((orig & 7) * (nwg >> 3) + (orig >> 3)) : orig;
    const int bm = (wg / nx) * 128, bn = (wg % nx) * 128;

    const int t = threadIdx.x;
    const int w = t >> 6, lane = t & 63;
    const int wr = (w >> 1) * 64, wc = (w & 1) * 64;
    const int l16 = lane & 15, lk = lane >> 4;

    // staging: lane -> (row srow, 16B chunk); source chunk XOR by (srow>>1)&3
    const int srow = lane >> 2;
    const int schunk = (lane & 3) ^ ((srow >> 1) & 3);
    // fragment-read chunk (same involution)
    const int ca = (lk ^ ((l16 >> 1) & 3)) * 8;

    f32x4 acc[4][4] = {};

    auto stage = [&](int buf, int kt) {
        __bf16* la = (__bf16*)(smem + buf * 16384);
        __bf16* lb = la + 4096;
        #pragma unroll
        for (int jj = 0; jj < 2; ++jj) {
            const __bf16* ga = Ab + (size_t)(bm + w * 32 + jj * 16 + srow) * ldk + kt + schunk * 8;
            __builtin_amdgcn_global_load_lds((gvoid_t*)ga, (lvoid_t*)&la[(w * 32 + jj * 16) * 32], 16, 0, 0);
            const __bf16* gb = Bb + (size_t)(bn + w * 32 + jj * 16 + srow) * ldk + kt + schunk * 8;
            __builtin_amdgcn_global_load_lds((gvoid_t*)gb, (lvoid_t*)&lb[(w * 32 + jj * 16) * 32], 16, 0, 0);
        }
    };

    stage(0, 0);
    __syncthreads();
    int cur = 0;
    for (int kt = 0; kt < Klen; kt += 32) {
        if (kt + 32 < Klen) stage(cur ^ 1, kt + 32);
        __bf16* la = (__bf16*)(smem + cur * 16384);
        __bf16* lb = la + 4096;
        bf16x8 af[4], bfr[4];
        #pragma unroll
        for (int i = 0; i < 4; ++i) {
            af[i]  = *reinterpret_cast<const bf16x8*>(&la[(wr + i * 16 + l16) * 32 + ca]);
            bfr[i] = *reinterpret_cast<const bf16x8*>(&lb[(wc + i * 16 + l16) * 32 + ca]);
        }
        #pragma unroll
        for (int mi = 0; mi < 4; ++mi)
            #pragma unroll
            for (int ni = 0; ni < 4; ++ni)
                acc[mi][ni] = __builtin_amdgcn_mfma_f32_16x16x32_bf16(af[mi], bfr[ni], acc[mi][ni], 0, 0, 0);
        __syncthreads();
        cur ^= 1;
    }

    if (vt && bn >= 1024) {
        // V third of QKV: store transposed into vt[b][h][d][s], 8B stores.
        const int bb = bm >> 9;
        const int s0 = (bm & 511) + wr + lk * 4;
        #pragma unroll
        for (int ni = 0; ni < 4; ++ni) {
            int c = bn + wc + ni * 16 + l16;
            float bv = biasb ? biasb[c] : 0.f;
            int hh = (c - 1024) >> 6, d = c & 63;
            __bf16* vrow = vt + ((size_t)(bb * 8 + hh) * 64 + d) * 512;
            #pragma unroll
            for (int mi = 0; mi < 4; ++mi) {
                bf16x4 o;
                #pragma unroll
                for (int j = 0; j < 4; ++j) o[j] = (__bf16)(acc[mi][ni][j] + bv);
                *reinterpret_cast<bf16x4*>(vrow + s0 + mi * 16) = o;
            }
        }
        return;
    }

    if (CbO) {
        #pragma unroll
        for (int ni = 0; ni < 4; ++ni) {
            int col = wc + ni * 16 + l16;
            float bv = biasb ? biasb[bn + col] : 0.f;
            #pragma unroll
            for (int mi = 0; mi < 4; ++mi)
                #pragma unroll
                for (int j = 0; j < 4; ++j) {
                    float v = acc[mi][ni][j] + bv;
                    if (relu) v = fmaxf(v, 0.f);
                    lCb[(wr + mi * 16 + lk * 4 + j) * 128 + col] = (__bf16)v;
                }
        }
        __syncthreads();
        #pragma unroll
        for (int it = 0; it < 8; ++it) {
            int off = it * 2048 + t * 8;
            int rl = off >> 7, col = off & 127;
            *reinterpret_cast<int4v*>(CbO + (size_t)(bm + rl) * ldc + bn + col) =
                *reinterpret_cast<const int4v*>(&lCb[off]);
        }
    } else {
        #pragma unroll
        for (int p = 0; p < 2; ++p) {
            if (p) __syncthreads();
            if (wr == p * 64) {
                #pragma unroll
                for (int ni = 0; ni < 4; ++ni) {
                    int col = wc + ni * 16 + l16;
                    float bv = biasb ? biasb[bn + col] : 0.f;
                    #pragma unroll
                    for (int mi = 0; mi < 4; ++mi)
                        #pragma unroll
                        for (int j = 0; j < 4; ++j) {
                            float v = acc[mi][ni][j] + bv;
                            if (relu) v = fmaxf(v, 0.f);
                            lCf[(mi * 16 + lk * 4 + j) * 128 + col] = v;
                        }
                }
            }
            __syncthreads();
            #pragma unroll
            for (int it = 0; it < 8; ++it) {
                int off = it * 1024 + t * 4;
                int rl = off >> 7, col = off & 127;
                *reinterpret_cast<f32x4*>(CfO + (size_t)(bm + p * 64 + rl) * ldc + bn + col) =
                    *reinterpret_cast<const f32x4*>(&lCf[off]);
            }
        }
    }
}

// ---------------------------------------------------------------- attention
// Variant C (r8 winner): grid (256 bh, 4 qt), 32 q-rows/wave, K and V both
// double-buffer staged in LDS via global_load_lds (pre-swizzled source).
// LDS 22.5KB, natural VGPR 64 -> 6 blocks/CU.
__global__ __launch_bounds__(256, 6)
void attn_fwd_c(const __bf16* __restrict__ qkv, const __bf16* __restrict__ vt,
                const int* __restrict__ mask, __bf16* __restrict__ out)
{
    __shared__ __bf16 lK[2][64 * 64];
    __shared__ __bf16 lV[2][64 * 64];
    __shared__ __bf16 lP[4][16 * 32];
    __shared__ float lM2[512];

    const int bh = blockIdx.x;
    const int b = bh >> 3, h = bh & 7;
    const int q0 = blockIdx.y * 128;
    const int t = threadIdx.x, w = t >> 6, lane = t & 63;
    const int l16 = lane & 15, lk = lane >> 4;

    const __bf16* qbase = qkv + (size_t)b * 512 * 1536 + h * 64;
    const __bf16* kbase = qbase + 512;
    const __bf16* vtb = vt + (size_t)(b * 8 + h) * 64 * 512;

    bf16x8 qfr[2][2];
    #pragma unroll
    for (int qn = 0; qn < 2; ++qn) {
        int row = q0 + w * 32 + qn * 16 + l16;
        #pragma unroll
        for (int kc = 0; kc < 2; ++kc)
            qfr[qn][kc] = *reinterpret_cast<const bf16x8*>(qbase + (size_t)row * 1536 + (kc * 4 + lk) * 8);
    }
    {
        int i0 = t * 2;
        lM2[i0]     = (mask[b * 512 + i0] == 0)     ? -2e9f : 0.f;
        lM2[i0 + 1] = (mask[b * 512 + i0 + 1] == 0) ? -2e9f : 0.f;
    }

    auto stageKV = [&](int buf, int kt) {
        #pragma unroll
        for (int r = 0; r < 2; ++r) {
            int c = r * 256 + w * 64 + lane;
            int row = c >> 3, ch = c & 7;
            const __bf16* ga = kbase + (size_t)(kt + row) * 1536 + ((ch ^ (row & 7)) * 8);
            __builtin_amdgcn_global_load_lds((gvoid_t*)ga,
                (lvoid_t*)(&lK[buf][0] + (r * 256 + w * 64) * 8), 16, 0, 0);
            const __bf16* gv = vtb + (size_t)row * 512 + kt + ((ch ^ (row & 7)) * 8);
            __builtin_amdgcn_global_load_lds((gvoid_t*)gv,
                (lvoid_t*)(&lV[buf][0] + (r * 256 + w * 64) * 8), 16, 0, 0);
        }
    };

    float m_run[2] = {-1e30f, -1e30f}, l_run[2] = {0.f, 0.f};
    f32x4 oacc[2][4] = {};
    const int xsw = ((l16 >> 1) & 3) << 1;

    stageKV(0, 0);
    __syncthreads();

    int cur = 0;
    for (int kt = 0; kt < 512; kt += 64) {
        if (kt + 64 < 512) stageKV(cur ^ 1, kt + 64);
        const __bf16* lKc = &lK[cur][0];
        const __bf16* lVc = &lV[cur][0];
        __bf16* lp = &lP[w][0];

        #pragma unroll
        for (int qn = 0; qn < 2; ++qn) {
            f32x4 sacc[4] = {};
            #pragma unroll
            for (int ni = 0; ni < 4; ++ni) {
                int krow = ni * 16 + l16;
                #pragma unroll
                for (int kc = 0; kc < 2; ++kc) {
                    bf16x8 kf = *reinterpret_cast<const bf16x8*>(&lKc[krow * 64 + (((kc * 4 + lk) ^ (krow & 7)) * 8)]);
                    sacc[ni] = __builtin_amdgcn_mfma_f32_16x16x32_bf16(kf, qfr[qn][kc], sacc[ni], 0, 0, 0);
                }
            }

            f32x4 mx4 = {-3e38f, -3e38f, -3e38f, -3e38f};
            #pragma unroll
            for (int ni = 0; ni < 4; ++ni) {
                f32x4 mkv = *reinterpret_cast<const f32x4*>(&lM2[kt + ni * 16 + lk * 4]);
                f32x4 sv;
                #pragma unroll
                for (int j = 0; j < 4; ++j) {
                    sv[j] = fmaf(sacc[ni][j], C1SM, mkv[j]);
                    mx4[j] = fmaxf(mx4[j], sv[j]);
                }
                sacc[ni] = sv;
            }
            float mx = fmaxf(fmaxf(mx4[0], mx4[1]), fmaxf(mx4[2], mx4[3]));
            mx = fmaxf(mx, __shfl_xor(mx, 16));
            mx = fmaxf(mx, __shfl_xor(mx, 32));
            bool need = mx > m_run[qn] + 11.54f;
            if (__any((int)need)) {
                float mn = fmaxf(m_run[qn], mx);
                float alpha = exp2f(m_run[qn] - mn);
                m_run[qn] = mn;
                l_run[qn] *= alpha;
                #pragma unroll
                for (int j = 0; j < 4; ++j) {
                    float aj = __shfl(alpha, lk * 4 + j);
                    #pragma unroll
                    for (int dn = 0; dn < 4; ++dn) oacc[qn][dn][j] *= aj;
                }
            }
            f32x4 ps4 = {0.f, 0.f, 0.f, 0.f};
            #pragma unroll
            for (int ni = 0; ni < 4; ++ni)
                #pragma unroll
                for (int j = 0; j < 4; ++j) {
                    float p = exp2f(sacc[ni][j] - m_run[qn]);
                    sacc[ni][j] = p;
                    ps4[j] += p;
                }
            l_run[qn] += (ps4[0] + ps4[1]) + (ps4[2] + ps4[3]);

            #pragma unroll
            for (int kc = 0; kc < 2; ++kc) {
                #pragma unroll
                for (int n2 = 0; n2 < 2; ++n2) {
                    bf16x4 o;
                    #pragma unroll
                    for (int j = 0; j < 4; ++j) o[j] = (__bf16)sacc[kc * 2 + n2][j];
                    *reinterpret_cast<bf16x4*>(&lp[l16 * 32 + ((n2 * 4 + lk) ^ xsw) * 4]) = o;
                }
                bf16x8 pf = *reinterpret_cast<const bf16x8*>(&lp[l16 * 32 + (lk ^ (xsw >> 1)) * 8]);
                #pragma unroll
                for (int dn = 0; dn < 4; ++dn) {
                    int vrow = dn * 16 + l16;
                    bf16x8 vf = *reinterpret_cast<const bf16x8*>(&lVc[vrow * 64 + (((kc * 4 + lk) ^ (vrow & 7)) * 8)]);
                    oacc[qn][dn] = __builtin_amdgcn_mfma_f32_16x16x32_bf16(pf, vf, oacc[qn][dn], 0, 0, 0);
                }
            }
        }
        __syncthreads();
        cur ^= 1;
    }

    #pragma unroll
    for (int qn = 0; qn < 2; ++qn) {
        float s = l_run[qn];
        s += __shfl_xor(s, 16);
        s += __shfl_xor(s, 32);
        float linv = 1.f / s;
        #pragma unroll
        for (int j = 0; j < 4; ++j) {
            float lj = __shfl(linv, lk * 4 + j);
            #pragma unroll
            for (int dn = 0; dn < 4; ++dn) {
                int row = q0 + w * 32 + qn * 16 + lk * 4 + j;
                int col = h * 64 + dn * 16 + l16;
                out[(size_t)(b * 512 + row) * 512 + col] = (__bf16)(oacc[qn][dn][j] * lj);
            }
        }
    }
}

// ---------------------------------------------------------------- elementwise

__device__ __forceinline__ float wsum64(float v)
{
    #pragma unroll
    for (int d = 32; d >= 1; d >>= 1) v += __shfl_xor(v, d);
    return v;
}

// x = LN(resid + projA + projB) * gamma + beta; bf16 residual stream, in-place.
__global__ __launch_bounds__(256)
void ln_fuse2(const __bf16* resid, const __bf16* __restrict__ pA,
              const __bf16* __restrict__ pB,
              const float* __restrict__ gamma, const float* __restrict__ beta,
              __bf16* xbo)
{
    int tok = blockIdx.x * 4 + (threadIdx.x >> 6);
    int lane = threadIdx.x & 63;
    size_t base = (size_t)tok * 512 + lane * 8;
    float y[8];
    {
        bf16x8 rv = *reinterpret_cast<const bf16x8*>(resid + base);
        bf16x8 pa = *reinterpret_cast<const bf16x8*>(pA + base);
        bf16x8 pb = *reinterpret_cast<const bf16x8*>(pB + base);
        #pragma unroll
        for (int i = 0; i < 8; ++i) y[i] = (float)rv[i] + (float)pa[i] + (float)pb[i];
    }
    float s = 0.f;
    #pragma unroll
    for (int i = 0; i < 8; ++i) s += y[i];
    float mean = wsum64(s) * (1.f / 512.f);
    float v = 0.f;
    #pragma unroll
    for (int i = 0; i < 8; ++i) { float d = y[i] - mean; v += d * d; }
    float rstd = rsqrtf(wsum64(v) * (1.f / 512.f) + 1e-5f);
    int hh = lane * 8;
    f32x4 g0 = *reinterpret_cast<const f32x4*>(gamma + hh);
    f32x4 g1 = *reinterpret_cast<const f32x4*>(gamma + hh + 4);
    f32x4 b0 = *reinterpret_cast<const f32x4*>(beta + hh);
    f32x4 b1 = *reinterpret_cast<const f32x4*>(beta + hh + 4);
    bf16x8 ob;
    #pragma unroll
    for (int i = 0; i < 4; ++i) {
        ob[i]     = (__bf16)((y[i] - mean) * rstd * g0[i] + b0[i]);
        ob[4 + i] = (__bf16)((y[4 + i] - mean) * rstd * g1[i] + b1[i]);
    }
    *reinterpret_cast<bf16x8*>(xbo + base) = ob;
}

// x = relu(LN(se)*g+b) + act_emb[g,a] + rtg*retW + retb + time_emb[t] + game_emb[g]
__global__ __launch_bounds__(256)
void embed_fin(const __bf16* __restrict__ seraw, const int* __restrict__ gi,
               const int* __restrict__ actions, const float* __restrict__ rtg,
               const int* __restrict__ ts,
               const float* __restrict__ olg, const float* __restrict__ olb,
               const float* __restrict__ act_emb, const float* __restrict__ retW,
               const float* __restrict__ retb, const float* __restrict__ time_emb,
               const float* __restrict__ game_emb,
               __bf16* __restrict__ xbo)
{
    int tok = blockIdx.x * 4 + (threadIdx.x >> 6);
    int lane = threadIdx.x & 63;
    int b = tok >> 9;
    int g = gi[b];
    int a = actions[tok];
    int tt = ts[tok];
    float rv = rtg[tok];
    size_t base = (size_t)tok * 512 + lane * 8;
    int hh = lane * 8;

    float y[8];
    {
        bf16x8 a0 = *reinterpret_cast<const bf16x8*>(seraw + base);
        #pragma unroll
        for (int i = 0; i < 8; ++i) y[i] = (float)a0[i];
    }
    float s = 0.f;
    #pragma unroll
    for (int i = 0; i < 8; ++i) s += y[i];
    float mean = wsum64(s) * (1.f / 512.f);
    float v = 0.f;
    #pragma unroll
    for (int i = 0; i < 8; ++i) { float d = y[i] - mean; v += d * d; }
    float rstd = rsqrtf(wsum64(v) * (1.f / 512.f) + 1e-5f);

    const float* gp = olg + (size_t)g * 512 + hh;
    const float* bp = olb + (size_t)g * 512 + hh;
    const float* ap = act_emb + ((size_t)g * 18 + a) * 512 + hh;
    const float* tp = time_emb + (size_t)tt * 512 + hh;
    const float* ep = game_emb + (size_t)g * 512 + hh;
    const float* rwp = retW + hh;
    const float* rbp = retb + hh;

    bf16x8 ob;
    #pragma unroll
    for (int half = 0; half < 2; ++half) {
        f32x4 gv = *reinterpret_cast<const f32x4*>(gp + half * 4);
        f32x4 bv = *reinterpret_cast<const f32x4*>(bp + half * 4);
        f32x4 av = *reinterpret_cast<const f32x4*>(ap + half * 4);
        f32x4 tv = *reinterpret_cast<const f32x4*>(tp + half * 4);
        f32x4 ev = *reinterpret_cast<const f32x4*>(ep + half * 4);
        f32x4 rw = *reinterpret_cast<const f32x4*>(rwp + half * 4);
        f32x4 rb = *reinterpret_cast<const f32x4*>(rbp + half * 4);
        #pragma unroll
        for (int i = 0; i < 4; ++i) {
            float n = (y[half * 4 + i] - mean) * rstd * gv[i] + bv[i];
            n = fmaxf(n, 0.f);
            float o = n + av[i] + rv * rw[i] + rb[i] + tv[i] + ev[i];
            ob[half * 4 + i] = (__bf16)o;
        }
    }
    *reinterpret_cast<bf16x8*>(xbo + base) = ob;
}

// action (18) + return (1) heads; wave per token, shuffle-reduce dots. bf16 x.
__global__ __launch_bounds__(256)
void head_ar(const __bf16* __restrict__ xbv, const int* __restrict__ gi,
             const float* __restrict__ ahWt, const float* __restrict__ ah_b,
             const float* __restrict__ rhW, const float* __restrict__ rhb,
             float* __restrict__ outA, float* __restrict__ outR)
{
    int tok = blockIdx.x * 4 + (threadIdx.x >> 6);
    int lane = threadIdx.x & 63;
    int b = tok >> 9;
    int g = gi[b];
    size_t base = (size_t)tok * 512 + lane * 8;
    float x[8];
    {
        bf16x8 a0 = *reinterpret_cast<const bf16x8*>(xbv + base);
        #pragma unroll
        for (int i = 0; i < 8; ++i) x[i] = (float)a0[i];
    }
    #pragma unroll 1
    for (int a = 0; a < 18; ++a) {
        const float* wp = ahWt + ((size_t)g * 18 + a) * 512 + lane * 8;
        f32x4 w0 = *reinterpret_cast<const f32x4*>(wp);
        f32x4 w1 = *reinterpret_cast<const f32x4*>(wp + 4);
        float p = 0.f;
        #pragma unroll
        for (int i = 0; i < 4; ++i) { p += x[i] * w0[i]; p += x[4 + i] * w1[i]; }
        p = wsum64(p);
        if (lane == 0) outA[(size_t)tok * 18 + a] = p + ah_b[g * 18 + a];
    }
    {
        const float* wp = rhW + lane * 8;
        f32x4 w0 = *reinterpret_cast<const f32x4*>(wp);
        f32x4 w1 = *reinterpret_cast<const f32x4*>(wp + 4);
        float p = 0.f;
        #pragma unroll
        for (int i = 0; i < 4; ++i) { p += x[i] * w0[i]; p += x[4 + i] * w1[i]; }
        p = wsum64(p);
        if (lane == 0) outR[tok] = p + rhb[0];
    }
}

// ---------------------------------------------------------------- launch

extern "C" void kernel_launch(void* const* d_in, const int* in_sizes, int n_in,
                              void* d_out, int out_size, void* d_ws, size_t ws_size,
                              hipStream_t stream)
{
    (void)in_sizes; (void)n_in; (void)out_size; (void)ws_size;

    const int*   gi       = (const int*)d_in[0];
    const float* states   = (const float*)d_in[1];
    const int*   actions  = (const int*)d_in[2];
    const float* rtg      = (const float*)d_in[3];
    const int*   ts       = (const int*)d_in[4];
    const int*   amask    = (const int*)d_in[5];
    const float* game_emb = (const float*)d_in[6];
    const float* obs_W    = (const float*)d_in[7];
    const float* obs_b    = (const float*)d_in[8];
    const float* obs_ln_g = (const float*)d_in[9];
    const float* obs_ln_b = (const float*)d_in[10];
    const float* act_emb  = (const float*)d_in[11];
    const float* ret_W    = (const float*)d_in[12];
    const float* ret_b    = (const float*)d_in[13];
    const float* time_emb = (const float*)d_in[14];
    const float* Wqkv     = (const float*)d_in[15];
    const float* bqkv     = (const float*)d_in[16];
    const float* Wo       = (const float*)d_in[17];
    const float* bo       = (const float*)d_in[18];
    const float* ln1_g    = (const float*)d_in[19];
    const float* ln1_b    = (const float*)d_in[20];
    const float* W1       = (const float*)d_in[21];
    const float* b1       = (const float*)d_in[22];
    const float* W2       = (const float*)d_in[23];
    const float* b2       = (const float*)d_in[24];
    const float* ln2_g    = (const float*)d_in[25];
    const float* ln2_b    = (const float*)d_in[26];
    const float* sh_W     = (const float*)d_in[27];
    const float* sh_b     = (const float*)d_in[28];
    const float* ah_W     = (const float*)d_in[29];
    const float* ah_b     = (const float*)d_in[30];
    const float* rh_W     = (const float*)d_in[31];
    const float* rh_b     = (const float*)d_in[32];

    char* wsb = (char*)d_ws;
    __bf16* tmp     = (__bf16*)(wsb + 0);                      // 16 MiB (proj partial A)
    __bf16* tmp2    = tmp + 8388608;                           // 16 MiB (proj partial B)
    __bf16* xb      = (__bf16*)(wsb + 33554432);               // 16 MiB bf16 residual stream
    __bf16* vT      = (__bf16*)(wsb + 67108864);               // 16 MiB  [b][h][d][s]
    __bf16* qkvB    = (__bf16*)(wsb + 83886080);               // region R1 (64 MiB): qkv / ff1 / states
    __bf16* ff1B    = qkvB;
    __bf16* statesB = qkvB;
    __bf16* obswB   = (__bf16*)(wsb + 83886080 + 8388608);
    __bf16* attnB   = (__bf16*)(wsb + 150994944);              // 16 MiB
    __bf16* wqkvB   = (__bf16*)(wsb + 167772160);
    __bf16* woB     = (__bf16*)(wsb + 177209344);
    __bf16* w1B     = (__bf16*)(wsb + 180355072);
    __bf16* w2B     = (__bf16*)(wsb + 192937984);
    __bf16* shwB    = (__bf16*)(wsb + 205520896);
    float*  ahwT    = (float*)(wsb + 207618048);

    cvt_f32_bf16<<<4608, 256, 0, stream>>>(Wqkv, wqkvB, 1179648);
    cvt_f32_bf16<<<1536, 256, 0, stream>>>(Wo, woB, 393216);
    cvt_f32_bf16<<<6144, 256, 0, stream>>>(W1, w1B, 1572864);
    cvt_f32_bf16<<<6144, 256, 0, stream>>>(W2, w2B, 1572864);
    cvt_f32_bf16<<<4096, 256, 0, stream>>>(states, statesB, 1048576);
    transpose_cvt<<<dim3(512, 8), 256, 0, stream>>>(obs_W, obswB, 256, 512);
    transpose_cvt<<<dim3(512, 8), 256, 0, stream>>>(sh_W, shwB, 512, 256);
    transpose_f32<<<dim3(36, 8), 256, 0, stream>>>(ah_W, ahwT, 512, 18);

    // embedding: se_raw = states @ obs_W[g] + obs_b[g]  (grouped, z=batch)
    gemm_bt<<<dim3(4, 4, 32), 256, 0, stream>>>(
        statesB, (size_t)512 * 256, obswB, (size_t)512 * 256, obs_b, 512,
        nullptr, tmp, (size_t)512 * 512, gi, 256, 256, 0, 512, 0, nullptr);
    embed_fin<<<4096, 256, 0, stream>>>(tmp, gi, actions, rtg, ts,
        obs_ln_g, obs_ln_b, act_emb, ret_W, ret_b, time_emb, game_emb, xb);

    for (int l = 0; l < 6; ++l) {
        // QKV (V third written transposed into vT)
        gemm_bt<<<dim3(12, 128, 1), 256, 0, stream>>>(
            xb, 0, wqkvB + (size_t)l * 1536 * 512, 0, bqkv + l * 1536, 0,
            nullptr, qkvB, 0, nullptr, 512, 512, 0, 1536, 0, vT);
        // attention
        attn_fwd_c<<<dim3(256, 4, 1), 256, 0, stream>>>(qkvB, vT, amask, attnB);
        // Wo projection, split-K=2 (z = K-half; bias on z=0; partials tmp/tmp2)
        gemm_bt<<<dim3(4, 128, 2), 256, 0, stream>>>(
            attnB, 0, woB + (size_t)l * 512 * 512, 0, bo + l * 512, 0,
            nullptr, tmp, 0, nullptr, 512, 256, 8388608, 512, 0, nullptr);
        ln_fuse2<<<4096, 256, 0, stream>>>(xb, tmp, tmp2, ln1_g + l * 512, ln1_b + l * 512, xb);
        // FF1 (relu, bf16 out)
        gemm_bt<<<dim3(16, 128, 1), 256, 0, stream>>>(
            xb, 0, w1B + (size_t)l * 2048 * 512, 0, b1 + l * 2048, 0,
            nullptr, ff1B, 0, nullptr, 512, 512, 0, 2048, 1, nullptr);
        // FF2, split-K=2
        gemm_bt<<<dim3(4, 128, 2), 256, 0, stream>>>(
            ff1B, 0, w2B + (size_t)l * 512 * 2048, 0, b2 + l * 512, 0,
            nullptr, tmp, 0, nullptr, 2048, 1024, 8388608, 512, 0, nullptr);
        ln_fuse2<<<4096, 256, 0, stream>>>(xb, tmp, tmp2, ln2_g + l * 512, ln2_b + l * 512, xb);
    }

    // state head (grouped, writes d_out[0 : 32*512*256))
    gemm_bt<<<dim3(2, 4, 32), 256, 0, stream>>>(
        xb, (size_t)512 * 512, shwB, (size_t)256 * 512, sh_b, 256,
        (float*)d_out, nullptr, (size_t)512 * 256, gi, 512, 512, 0, 256, 0, nullptr);
    // action + return heads
    head_ar<<<4096, 256, 0, stream>>>(xb, gi, ahwT, ah_b, rh_W, rh_b,
        (float*)d_out + 4194304, (float*)d_out + 4489216);
}

// Round 12
// 1386.974 us; speedup vs baseline: 1.1312x; 1.0274x over previous
//
#include <hip/hip_runtime.h>

typedef __bf16 bf16x4 __attribute__((ext_vector_type(4)));
typedef __bf16 bf16x8 __attribute__((ext_vector_type(8)));
typedef float f32x4 __attribute__((ext_vector_type(4)));
typedef int int4v __attribute__((ext_vector_type(4)));

#define C1SM  0.18033688011112042592f   /* 0.125 * log2(e) */

typedef const __attribute__((address_space(1))) void gvoid_t;
typedef __attribute__((address_space(3))) void lvoid_t;

#define SBAR()  asm volatile("s_barrier" ::: "memory")
#define WV0()   asm volatile("s_waitcnt vmcnt(0)" ::: "memory")
#define WLG0()  asm volatile("s_waitcnt lgkmcnt(0)" ::: "memory")

// ---------------------------------------------------------------- converts

__global__ void cvt_f32_bf16(const float* __restrict__ src, __bf16* __restrict__ dst, int n4)
{
    int i = blockIdx.x * blockDim.x + threadIdx.x;
    if (i >= n4) return;
    f32x4 v = *reinterpret_cast<const f32x4*>(src + (size_t)i * 4);
    bf16x4 o;
    #pragma unroll
    for (int k = 0; k < 4; ++k) o[k] = (__bf16)v[k];
    *reinterpret_cast<bf16x4*>(dst + (size_t)i * 4) = o;
}

// src (nmat, R, C) -> dst (nmat, C, R), bf16
__global__ void transpose_cvt(const float* __restrict__ src, __bf16* __restrict__ dst, int R, int C)
{
    int m = blockIdx.y;
    int n = R * C;
    int i = blockIdx.x * 256 + threadIdx.x;
    if (i >= n) return;
    int c = i / R, r = i - c * R;
    dst[(size_t)m * n + i] = (__bf16)src[(size_t)m * n + (size_t)r * C + c];
}

// src (nmat, R, C) -> dst (nmat, C, R), f32
__global__ void transpose_f32(const float* __restrict__ src, float* __restrict__ dst, int R, int C)
{
    int m = blockIdx.y;
    int n = R * C;
    int i = blockIdx.x * 256 + threadIdx.x;
    if (i >= n) return;
    int c = i / R, r = i - c * R;
    dst[(size_t)m * n + i] = src[(size_t)m * n + (size_t)r * C + c];
}

// ---------------------------------------------------------------- GEMM 256x256 (FF1)
// C[m][n] = relu(sum_k A[m][k]*B[n][k] + bias[n]), K=512 hardcoded.
// 8 waves (2M x 4N), per-wave 128x64 out. LDS 128KB = 2 K-tile slots
// (A 256x64 + B 256x64 each), swizzled ch^=(row&7). Stage(kt+1) issued at
// K-tile start (latency hidden under 4 quadrant phases); vmcnt(0)+s_barrier
// only at K-tile boundaries; per-phase light barriers + setprio around MFMA.
__global__ __launch_bounds__(512, 2)
void gemm256(const __bf16* __restrict__ A, const __bf16* __restrict__ B,
             const float* __restrict__ bias, __bf16* __restrict__ C,
             int ldc, int relu)
{
    __shared__ __bf16 lds[65536];   // 128 KB

    const int t = threadIdx.x;
    const int w = t >> 6, lane = t & 63;
    const int l16 = lane & 15, lk = lane >> 4;
    const int wrl = (w >> 2) * 128;     // wave M offset (0/128)
    const int wcl = (w & 3) * 64;       // wave N offset (0/64/128/192)

    // XCD swizzle
    const int nx = gridDim.x;
    const int nwg = nx * gridDim.y;
    int orig = blockIdx.y * nx + blockIdx.x;
    int wg = ((nwg & 7) == 0) ? ((orig & 7) * (nwg >> 3) + (orig >> 3)) : orig;
    const int bm = (wg / nx) * 256, bn = (wg % nx) * 256;

    const __bf16* Ab = A + (size_t)bm * 512;
    const __bf16* Bb = B + (size_t)bn * 512;

    f32x4 acc[8][4] = {};
    bf16x8 af[4][2], bfr[2][2];

    auto stageKt = [&](int kt) {
        const int slot = kt & 1;
        #pragma unroll
        for (int h = 0; h < 4; ++h) {
            const int m = h >> 1, hf = h & 1;
            const __bf16* src = m ? Bb : Ab;
            __bf16* lb = lds + slot * 32768 + m * 16384 + hf * 8192;
            #pragma unroll
            for (int i = 0; i < 2; ++i) {
                int u = i * 512 + t;
                int row = hf * 128 + (u >> 3);
                int ch = (u & 7) ^ (row & 7);
                const __bf16* ga = src + (size_t)row * 512 + kt * 64 + ch * 8;
                __builtin_amdgcn_global_load_lds((gvoid_t*)ga,
                    (lvoid_t*)(lb + (i * 512 + w * 64) * 8), 16, 0, 0);
            }
        }
    };
    auto ldA = [&](int slot, int mh) {
        const __bf16* la = lds + slot * 32768;
        #pragma unroll
        for (int mi = 0; mi < 4; ++mi) {
            int row = wrl + mh * 64 + mi * 16 + l16;
            #pragma unroll
            for (int ks = 0; ks < 2; ++ks) {
                int c = (ks * 4 + lk) ^ (row & 7);
                af[mi][ks] = *reinterpret_cast<const bf16x8*>(la + row * 64 + c * 8);
            }
        }
    };
    auto ldB = [&](int slot, int nh) {
        const __bf16* lb = lds + slot * 32768 + 16384;
        #pragma unroll
        for (int nf = 0; nf < 2; ++nf) {
            int row = wcl + nh * 32 + nf * 16 + l16;
            #pragma unroll
            for (int ks = 0; ks < 2; ++ks) {
                int c = (ks * 4 + lk) ^ (row & 7);
                bfr[nf][ks] = *reinterpret_cast<const bf16x8*>(lb + row * 64 + c * 8);
            }
        }
    };
    auto quad = [&](int mh, int nh) {
        __builtin_amdgcn_s_setprio(1);
        #pragma unroll
        for (int mi = 0; mi < 4; ++mi)
            #pragma unroll
            for (int nf = 0; nf < 2; ++nf)
                #pragma unroll
                for (int ks = 0; ks < 2; ++ks)
                    acc[mh * 4 + mi][nh * 2 + nf] = __builtin_amdgcn_mfma_f32_16x16x32_bf16(
                        af[mi][ks], bfr[nf][ks], acc[mh * 4 + mi][nh * 2 + nf], 0, 0, 0);
        __builtin_amdgcn_s_setprio(0);
    };

    stageKt(0);
    #pragma unroll
    for (int kt = 0; kt < 8; ++kt) {
        const int slot = kt & 1;
        WV0();                      // kt's loads landed (per wave)
        SBAR();                     // all waves' loads landed
        if (kt < 7) stageKt(kt + 1);    // into other slot; hides under compute
        ldA(slot, 0); ldB(slot, 0);
        SBAR(); quad(0, 0); SBAR();
        ldB(slot, 1);
        SBAR(); quad(0, 1); SBAR();
        ldA(slot, 1);
        SBAR(); quad(1, 1); SBAR();
        ldB(slot, 0);
        SBAR(); quad(1, 0); SBAR();
    }

    // epilogue: bias(+relu), stage 256x256 bf16 in LDS, coalesced 512B rows
    SBAR();
    __bf16* lc = lds;
    #pragma unroll
    for (int nf = 0; nf < 4; ++nf) {
        int col = wcl + nf * 16 + l16;
        float bv = bias[bn + col];
        #pragma unroll
        for (int mf = 0; mf < 8; ++mf)
            #pragma unroll
            for (int j = 0; j < 4; ++j) {
                float v = acc[mf][nf][j] + bv;
                if (relu) v = fmaxf(v, 0.f);
                lc[(wrl + mf * 16 + lk * 4 + j) * 256 + col] = (__bf16)v;
            }
    }
    WLG0();
    SBAR();
    #pragma unroll
    for (int i = 0; i < 16; ++i) {
        int off = i * 4096 + t * 8;
        int r = off >> 8, c2 = off & 255;
        *reinterpret_cast<int4v*>(C + (size_t)(bm + r) * ldc + bn + c2) =
            *reinterpret_cast<const int4v*>(lc + off);
    }
}

// ---------------------------------------------------------------- GEMM 128x128
// C[z][m][n] = sum_k A[.][m][k0+k] * B[.][n][k0+k] + bias[.][n]   (B^T layout)
// 128x128 tile, BK=32, dbuf global_load_lds staging, coalesced epilogue,
// XCD swizzle. Chunk-swizzle keyed on row bits 1-2 (free 2-way aliasing).
// 4 blocks/CU (5 thrashes L2: r10).
__global__ __launch_bounds__(256, 4)
void gemm_bt(const __bf16* __restrict__ A, size_t strideA,
             const __bf16* __restrict__ B, size_t strideB,
             const float* __restrict__ bias, int strideBias,
             float* Cf, __bf16* Cb, size_t strideC,
             const int* __restrict__ gidx, int ldk, int Klen,
             size_t splitStride, int ldc, int relu, __bf16* __restrict__ vt)
{
    __shared__ __align__(16) char smem[32768];
    __bf16* lCb = (__bf16*)smem;
    float*  lCf = (float*)smem;

    const int z = blockIdx.z;
    const int g = gidx ? gidx[z] : 0;
    const __bf16* Ab = A + (splitStride ? (size_t)z * Klen : (size_t)z * strideA);
    const __bf16* Bb = B + (splitStride ? (size_t)z * Klen : (size_t)g * strideB);
    __bf16* CbO = Cb ? (Cb + (size_t)z * (splitStride ? splitStride : strideC)) : nullptr;
    float*  CfO = Cf ? (Cf + (size_t)z * strideC) : nullptr;
    const float* biasb = (bias && (!splitStride || z == 0)) ? bias + (size_t)g * strideBias : nullptr;

    const int nx = gridDim.x;
    const int nwg = nx * gridDim.y;
    int orig = blockIdx.y * nx + blockIdx.x;
    int wg = ((nwg & 7) == 0) ? ((orig & 7) * (nwg >> 3) + (orig >> 3)) : orig;
    const int bm = (wg / nx) * 128, bn = (wg % nx) * 128;

    const int t = threadIdx.x;
    const int w = t >> 6, lane = t & 63;
    const int wr = (w >> 1) * 64, wc = (w & 1) * 64;
    const int l16 = lane & 15, lk = lane >> 4;

    const int srow = lane >> 2;
    const int schunk = (lane & 3) ^ ((srow >> 1) & 3);
    const int ca = (lk ^ ((l16 >> 1) & 3)) * 8;

    f32x4 acc[4][4] = {};

    auto stage = [&](int buf, int kt) {
        __bf16* la = (__bf16*)(smem + buf * 16384);
        __bf16* lb = la + 4096;
        #pragma unroll
        for (int jj = 0; jj < 2; ++jj) {
            const __bf16* ga = Ab + (size_t)(bm + w * 32 + jj * 16 + srow) * ldk + kt + schunk * 8;
            __builtin_amdgcn_global_load_lds((gvoid_t*)ga, (lvoid_t*)&la[(w * 32 + jj * 16) * 32], 16, 0, 0);
            const __bf16* gb = Bb + (size_t)(bn + w * 32 + jj * 16 + srow) * ldk + kt + schunk * 8;
            __builtin_amdgcn_global_load_lds((gvoid_t*)gb, (lvoid_t*)&lb[(w * 32 + jj * 16) * 32], 16, 0, 0);
        }
    };

    stage(0, 0);
    __syncthreads();
    int cur = 0;
    for (int kt = 0; kt < Klen; kt += 32) {
        if (kt + 32 < Klen) stage(cur ^ 1, kt + 32);
        __bf16* la = (__bf16*)(smem + cur * 16384);
        __bf16* lb = la + 4096;
        bf16x8 af[4], bfr[4];
        #pragma unroll
        for (int i = 0; i < 4; ++i) {
            af[i]  = *reinterpret_cast<const bf16x8*>(&la[(wr + i * 16 + l16) * 32 + ca]);
            bfr[i] = *reinterpret_cast<const bf16x8*>(&lb[(wc + i * 16 + l16) * 32 + ca]);
        }
        #pragma unroll
        for (int mi = 0; mi < 4; ++mi)
            #pragma unroll
            for (int ni = 0; ni < 4; ++ni)
                acc[mi][ni] = __builtin_amdgcn_mfma_f32_16x16x32_bf16(af[mi], bfr[ni], acc[mi][ni], 0, 0, 0);
        __syncthreads();
        cur ^= 1;
    }

    if (vt && bn >= 1024) {
        const int bb = bm >> 9;
        const int s0 = (bm & 511) + wr + lk * 4;
        #pragma unroll
        for (int ni = 0; ni < 4; ++ni) {
            int c = bn + wc + ni * 16 + l16;
            float bv = biasb ? biasb[c] : 0.f;
            int hh = (c - 1024) >> 6, d = c & 63;
            __bf16* vrow = vt + ((size_t)(bb * 8 + hh) * 64 + d) * 512;
            #pragma unroll
            for (int mi = 0; mi < 4; ++mi) {
                bf16x4 o;
                #pragma unroll
                for (int j = 0; j < 4; ++j) o[j] = (__bf16)(acc[mi][ni][j] + bv);
                *reinterpret_cast<bf16x4*>(vrow + s0 + mi * 16) = o;
            }
        }
        return;
    }

    if (CbO) {
        #pragma unroll
        for (int ni = 0; ni < 4; ++ni) {
            int col = wc + ni * 16 + l16;
            float bv = biasb ? biasb[bn + col] : 0.f;
            #pragma unroll
            for (int mi = 0; mi < 4; ++mi)
                #pragma unroll
                for (int j = 0; j < 4; ++j) {
                    float v = acc[mi][ni][j] + bv;
                    if (relu) v = fmaxf(v, 0.f);
                    lCb[(wr + mi * 16 + lk * 4 + j) * 128 + col] = (__bf16)v;
                }
        }
        __syncthreads();
        #pragma unroll
        for (int it = 0; it < 8; ++it) {
            int off = it * 2048 + t * 8;
            int rl = off >> 7, col = off & 127;
            *reinterpret_cast<int4v*>(CbO + (size_t)(bm + rl) * ldc + bn + col) =
                *reinterpret_cast<const int4v*>(&lCb[off]);
        }
    } else {
        #pragma unroll
        for (int p = 0; p < 2; ++p) {
            if (p) __syncthreads();
            if (wr == p * 64) {
                #pragma unroll
                for (int ni = 0; ni < 4; ++ni) {
                    int col = wc + ni * 16 + l16;
                    float bv = biasb ? biasb[bn + col] : 0.f;
                    #pragma unroll
                    for (int mi = 0; mi < 4; ++mi)
                        #pragma unroll
                        for (int j = 0; j < 4; ++j) {
                            float v = acc[mi][ni][j] + bv;
                            if (relu) v = fmaxf(v, 0.f);
                            lCf[(mi * 16 + lk * 4 + j) * 128 + col] = v;
                        }
                }
            }
            __syncthreads();
            #pragma unroll
            for (int it = 0; it < 8; ++it) {
                int off = it * 1024 + t * 4;
                int rl = off >> 7, col = off & 127;
                *reinterpret_cast<f32x4*>(CfO + (size_t)(bm + p * 64 + rl) * ldc + bn + col) =
                    *reinterpret_cast<const f32x4*>(&lCf[off]);
            }
        }
    }
}

// ---------------------------------------------------------------- attention
// Variant C (r8 winner, r9 config): grid (256 bh, 4 qt), 32 q-rows/wave,
// K and V double-buffer staged via global_load_lds (pre-swizzled source).
__global__ __launch_bounds__(256, 4)
void attn_fwd_c(const __bf16* __restrict__ qkv, const __bf16* __restrict__ vt,
                const int* __restrict__ mask, __bf16* __restrict__ out)
{
    __shared__ __bf16 lK[2][64 * 64];
    __shared__ __bf16 lV[2][64 * 64];
    __shared__ __bf16 lP[4][16 * 32];
    __shared__ float lM2[512];

    const int bh = blockIdx.x;
    const int b = bh >> 3, h = bh & 7;
    const int q0 = blockIdx.y * 128;
    const int t = threadIdx.x, w = t >> 6, lane = t & 63;
    const int l16 = lane & 15, lk = lane >> 4;

    const __bf16* qbase = qkv + (size_t)b * 512 * 1536 + h * 64;
    const __bf16* kbase = qbase + 512;
    const __bf16* vtb = vt + (size_t)(b * 8 + h) * 64 * 512;

    bf16x8 qfr[2][2];
    #pragma unroll
    for (int qn = 0; qn < 2; ++qn) {
        int row = q0 + w * 32 + qn * 16 + l16;
        #pragma unroll
        for (int kc = 0; kc < 2; ++kc)
            qfr[qn][kc] = *reinterpret_cast<const bf16x8*>(qbase + (size_t)row * 1536 + (kc * 4 + lk) * 8);
    }
    {
        int i0 = t * 2;
        lM2[i0]     = (mask[b * 512 + i0] == 0)     ? -2e9f : 0.f;
        lM2[i0 + 1] = (mask[b * 512 + i0 + 1] == 0) ? -2e9f : 0.f;
    }

    auto stageKV = [&](int buf, int kt) {
        #pragma unroll
        for (int r = 0; r < 2; ++r) {
            int c = r * 256 + w * 64 + lane;
            int row = c >> 3, ch = c & 7;
            const __bf16* ga = kbase + (size_t)(kt + row) * 1536 + ((ch ^ (row & 7)) * 8);
            __builtin_amdgcn_global_load_lds((gvoid_t*)ga,
                (lvoid_t*)(&lK[buf][0] + (r * 256 + w * 64) * 8), 16, 0, 0);
            const __bf16* gv = vtb + (size_t)row * 512 + kt + ((ch ^ (row & 7)) * 8);
            __builtin_amdgcn_global_load_lds((gvoid_t*)gv,
                (lvoid_t*)(&lV[buf][0] + (r * 256 + w * 64) * 8), 16, 0, 0);
        }
    };

    float m_run[2] = {-1e30f, -1e30f}, l_run[2] = {0.f, 0.f};
    f32x4 oacc[2][4] = {};
    const int xsw = ((l16 >> 1) & 3) << 1;

    stageKV(0, 0);
    __syncthreads();

    int cur = 0;
    for (int kt = 0; kt < 512; kt += 64) {
        if (kt + 64 < 512) stageKV(cur ^ 1, kt + 64);
        const __bf16* lKc = &lK[cur][0];
        const __bf16* lVc = &lV[cur][0];
        __bf16* lp = &lP[w][0];

        #pragma unroll
        for (int qn = 0; qn < 2; ++qn) {
            f32x4 sacc[4] = {};
            #pragma unroll
            for (int ni = 0; ni < 4; ++ni) {
                int krow = ni * 16 + l16;
                #pragma unroll
                for (int kc = 0; kc < 2; ++kc) {
                    bf16x8 kf = *reinterpret_cast<const bf16x8*>(&lKc[krow * 64 + (((kc * 4 + lk) ^ (krow & 7)) * 8)]);
                    sacc[ni] = __builtin_amdgcn_mfma_f32_16x16x32_bf16(kf, qfr[qn][kc], sacc[ni], 0, 0, 0);
                }
            }

            f32x4 mx4 = {-3e38f, -3e38f, -3e38f, -3e38f};
            #pragma unroll
            for (int ni = 0; ni < 4; ++ni) {
                f32x4 mkv = *reinterpret_cast<const f32x4*>(&lM2[kt + ni * 16 + lk * 4]);
                f32x4 sv;
                #pragma unroll
                for (int j = 0; j < 4; ++j) {
                    sv[j] = fmaf(sacc[ni][j], C1SM, mkv[j]);
                    mx4[j] = fmaxf(mx4[j], sv[j]);
                }
                sacc[ni] = sv;
            }
            float mx = fmaxf(fmaxf(mx4[0], mx4[1]), fmaxf(mx4[2], mx4[3]));
            mx = fmaxf(mx, __shfl_xor(mx, 16));
            mx = fmaxf(mx, __shfl_xor(mx, 32));
            bool need = mx > m_run[qn] + 11.54f;
            if (__any((int)need)) {
                float mn = fmaxf(m_run[qn], mx);
                float alpha = exp2f(m_run[qn] - mn);
                m_run[qn] = mn;
                l_run[qn] *= alpha;
                #pragma unroll
                for (int j = 0; j < 4; ++j) {
                    float aj = __shfl(alpha, lk * 4 + j);
                    #pragma unroll
                    for (int dn = 0; dn < 4; ++dn) oacc[qn][dn][j] *= aj;
                }
            }
            f32x4 ps4 = {0.f, 0.f, 0.f, 0.f};
            #pragma unroll
            for (int ni = 0; ni < 4; ++ni)
                #pragma unroll
                for (int j = 0; j < 4; ++j) {
                    float p = exp2f(sacc[ni][j] - m_run[qn]);
                    sacc[ni][j] = p;
                    ps4[j] += p;
                }
            l_run[qn] += (ps4[0] + ps4[1]) + (ps4[2] + ps4[3]);

            #pragma unroll
            for (int kc = 0; kc < 2; ++kc) {
                #pragma unroll
                for (int n2 = 0; n2 < 2; ++n2) {
                    bf16x4 o;
                    #pragma unroll
                    for (int j = 0; j < 4; ++j) o[j] = (__bf16)sacc[kc * 2 + n2][j];
                    *reinterpret_cast<bf16x4*>(&lp[l16 * 32 + ((n2 * 4 + lk) ^ xsw) * 4]) = o;
                }
                bf16x8 pf = *reinterpret_cast<const bf16x8*>(&lp[l16 * 32 + (lk ^ (xsw >> 1)) * 8]);
                #pragma unroll
                for (int dn = 0; dn < 4; ++dn) {
                    int vrow = dn * 16 + l16;
                    bf16x8 vf = *reinterpret_cast<const bf16x8*>(&lVc[vrow * 64 + (((kc * 4 + lk) ^ (vrow & 7)) * 8)]);
                    oacc[qn][dn] = __builtin_amdgcn_mfma_f32_16x16x32_bf16(pf, vf, oacc[qn][dn], 0, 0, 0);
                }
            }
        }
        __syncthreads();
        cur ^= 1;
    }

    #pragma unroll
    for (int qn = 0; qn < 2; ++qn) {
        float s = l_run[qn];
        s += __shfl_xor(s, 16);
        s += __shfl_xor(s, 32);
        float linv = 1.f / s;
        #pragma unroll
        for (int j = 0; j < 4; ++j) {
            float lj = __shfl(linv, lk * 4 + j);
            #pragma unroll
            for (int dn = 0; dn < 4; ++dn) {
                int row = q0 + w * 32 + qn * 16 + lk * 4 + j;
                int col = h * 64 + dn * 16 + l16;
                out[(size_t)(b * 512 + row) * 512 + col] = (__bf16)(oacc[qn][dn][j] * lj);
            }
        }
    }
}

// ---------------------------------------------------------------- elementwise

__device__ __forceinline__ float wsum64(float v)
{
    #pragma unroll
    for (int d = 32; d >= 1; d >>= 1) v += __shfl_xor(v, d);
    return v;
}

// x = LN(resid + projA + projB) * gamma + beta; bf16 residual stream, in-place.
__global__ __launch_bounds__(256)
void ln_fuse2(const __bf16* resid, const __bf16* __restrict__ pA,
              const __bf16* __restrict__ pB,
              const float* __restrict__ gamma, const float* __restrict__ beta,
              __bf16* xbo)
{
    int tok = blockIdx.x * 4 + (threadIdx.x >> 6);
    int lane = threadIdx.x & 63;
    size_t base = (size_t)tok * 512 + lane * 8;
    float y[8];
    {
        bf16x8 rv = *reinterpret_cast<const bf16x8*>(resid + base);
        bf16x8 pa = *reinterpret_cast<const bf16x8*>(pA + base);
        bf16x8 pb = *reinterpret_cast<const bf16x8*>(pB + base);
        #pragma unroll
        for (int i = 0; i < 8; ++i) y[i] = (float)rv[i] + (float)pa[i] + (float)pb[i];
    }
    float s = 0.f;
    #pragma unroll
    for (int i = 0; i < 8; ++i) s += y[i];
    float mean = wsum64(s) * (1.f / 512.f);
    float v = 0.f;
    #pragma unroll
    for (int i = 0; i < 8; ++i) { float d = y[i] - mean; v += d * d; }
    float rstd = rsqrtf(wsum64(v) * (1.f / 512.f) + 1e-5f);
    int hh = lane * 8;
    f32x4 g0 = *reinterpret_cast<const f32x4*>(gamma + hh);
    f32x4 g1 = *reinterpret_cast<const f32x4*>(gamma + hh + 4);
    f32x4 b0 = *reinterpret_cast<const f32x4*>(beta + hh);
    f32x4 b1 = *reinterpret_cast<const f32x4*>(beta + hh + 4);
    bf16x8 ob;
    #pragma unroll
    for (int i = 0; i < 4; ++i) {
        ob[i]     = (__bf16)((y[i] - mean) * rstd * g0[i] + b0[i]);
        ob[4 + i] = (__bf16)((y[4 + i] - mean) * rstd * g1[i] + b1[i]);
    }
    *reinterpret_cast<bf16x8*>(xbo + base) = ob;
}

// x = relu(LN(se)*g+b) + act_emb[g,a] + rtg*retW + retb + time_emb[t] + game_emb[g]
__global__ __launch_bounds__(256)
void embed_fin(const __bf16* __restrict__ seraw, const int* __restrict__ gi,
               const int* __restrict__ actions, const float* __restrict__ rtg,
               const int* __restrict__ ts,
               const float* __restrict__ olg, const float* __restrict__ olb,
               const float* __restrict__ act_emb, const float* __restrict__ retW,
               const float* __restrict__ retb, const float* __restrict__ time_emb,
               const float* __restrict__ game_emb,
               __bf16* __restrict__ xbo)
{
    int tok = blockIdx.x * 4 + (threadIdx.x >> 6);
    int lane = threadIdx.x & 63;
    int b = tok >> 9;
    int g = gi[b];
    int a = actions[tok];
    int tt = ts[tok];
    float rv = rtg[tok];
    size_t base = (size_t)tok * 512 + lane * 8;
    int hh = lane * 8;

    float y[8];
    {
        bf16x8 a0 = *reinterpret_cast<const bf16x8*>(seraw + base);
        #pragma unroll
        for (int i = 0; i < 8; ++i) y[i] = (float)a0[i];
    }
    float s = 0.f;
    #pragma unroll
    for (int i = 0; i < 8; ++i) s += y[i];
    float mean = wsum64(s) * (1.f / 512.f);
    float v = 0.f;
    #pragma unroll
    for (int i = 0; i < 8; ++i) { float d = y[i] - mean; v += d * d; }
    float rstd = rsqrtf(wsum64(v) * (1.f / 512.f) + 1e-5f);

    const float* gp = olg + (size_t)g * 512 + hh;
    const float* bp = olb + (size_t)g * 512 + hh;
    const float* ap = act_emb + ((size_t)g * 18 + a) * 512 + hh;
    const float* tp = time_emb + (size_t)tt * 512 + hh;
    const float* ep = game_emb + (size_t)g * 512 + hh;
    const float* rwp = retW + hh;
    const float* rbp = retb + hh;

    bf16x8 ob;
    #pragma unroll
    for (int half = 0; half < 2; ++half) {
        f32x4 gv = *reinterpret_cast<const f32x4*>(gp + half * 4);
        f32x4 bv = *reinterpret_cast<const f32x4*>(bp + half * 4);
        f32x4 av = *reinterpret_cast<const f32x4*>(ap + half * 4);
        f32x4 tv = *reinterpret_cast<const f32x4*>(tp + half * 4);
        f32x4 ev = *reinterpret_cast<const f32x4*>(ep + half * 4);
        f32x4 rw = *reinterpret_cast<const f32x4*>(rwp + half * 4);
        f32x4 rb = *reinterpret_cast<const f32x4*>(rbp + half * 4);
        #pragma unroll
        for (int i = 0; i < 4; ++i) {
            float n = (y[half * 4 + i] - mean) * rstd * gv[i] + bv[i];
            n = fmaxf(n, 0.f);
            float o = n + av[i] + rv * rw[i] + rb[i] + tv[i] + ev[i];
            ob[half * 4 + i] = (__bf16)o;
        }
    }
    *reinterpret_cast<bf16x8*>(xbo + base) = ob;
}

// action (18) + return (1) heads; wave per token, shuffle-reduce dots. bf16 x.
__global__ __launch_bounds__(256)
void head_ar(const __bf16* __restrict__ xbv, const int* __restrict__ gi,
             const float* __restrict__ ahWt, const float* __restrict__ ah_b,
             const float* __restrict__ rhW, const float* __restrict__ rhb,
             float* __restrict__ outA, float* __restrict__ outR)
{
    int tok = blockIdx.x * 4 + (threadIdx.x >> 6);
    int lane = threadIdx.x & 63;
    int b = tok >> 9;
    int g = gi[b];
    size_t base = (size_t)tok * 512 + lane * 8;
    float x[8];
    {
        bf16x8 a0 = *reinterpret_cast<const bf16x8*>(xbv + base);
        #pragma unroll
        for (int i = 0; i < 8; ++i) x[i] = (float)a0[i];
    }
    #pragma unroll 1
    for (int a = 0; a < 18; ++a) {
        const float* wp = ahWt + ((size_t)g * 18 + a) * 512 + lane * 8;
        f32x4 w0 = *reinterpret_cast<const f32x4*>(wp);
        f32x4 w1 = *reinterpret_cast<const f32x4*>(wp + 4);
        float p = 0.f;
        #pragma unroll
        for (int i = 0; i < 4; ++i) { p += x[i] * w0[i]; p += x[4 + i] * w1[i]; }
        p = wsum64(p);
        if (lane == 0) outA[(size_t)tok * 18 + a] = p + ah_b[g * 18 + a];
    }
    {
        const float* wp = rhW + lane * 8;
        f32x4 w0 = *reinterpret_cast<const f32x4*>(wp);
        f32x4 w1 = *reinterpret_cast<const f32x4*>(wp + 4);
        float p = 0.f;
        #pragma unroll
        for (int i = 0; i < 4; ++i) { p += x[i] * w0[i]; p += x[4 + i] * w1[i]; }
        p = wsum64(p);
        if (lane == 0) outR[tok] = p + rhb[0];
    }
}

// ---------------------------------------------------------------- launch

extern "C" void kernel_launch(void* const* d_in, const int* in_sizes, int n_in,
                              void* d_out, int out_size, void* d_ws, size_t ws_size,
                              hipStream_t stream)
{
    (void)in_sizes; (void)n_in; (void)out_size; (void)ws_size;

    const int*   gi       = (const int*)d_in[0];
    const float* states   = (const float*)d_in[1];
    const int*   actions  = (const int*)d_in[2];
    const float* rtg      = (const float*)d_in[3];
    const int*   ts       = (const int*)d_in[4];
    const int*   amask    = (const int*)d_in[5];
    const float* game_emb = (const float*)d_in[6];
    const float* obs_W    = (const float*)d_in[7];
    const float* obs_b    = (const float*)d_in[8];
    const float* obs_ln_g = (const float*)d_in[9];
    const float* obs_ln_b = (const float*)d_in[10];
    const float* act_emb  = (const float*)d_in[11];
    const float* ret_W    = (const float*)d_in[12];
    const float* ret_b    = (const float*)d_in[13];
    const float* time_emb = (const float*)d_in[14];
    const float* Wqkv     = (const float*)d_in[15];
    const float* bqkv     = (const float*)d_in[16];
    const float* Wo       = (const float*)d_in[17];
    const float* bo       = (const float*)d_in[18];
    const float* ln1_g    = (const float*)d_in[19];
    const float* ln1_b    = (const float*)d_in[20];
    const float* W1       = (const float*)d_in[21];
    const float* b1       = (const float*)d_in[22];
    const float* W2       = (const float*)d_in[23];
    const float* b2       = (const float*)d_in[24];
    const float* ln2_g    = (const float*)d_in[25];
    const float* ln2_b    = (const float*)d_in[26];
    const float* sh_W     = (const float*)d_in[27];
    const float* sh_b     = (const float*)d_in[28];
    const float* ah_W     = (const float*)d_in[29];
    const float* ah_b     = (const float*)d_in[30];
    const float* rh_W     = (const float*)d_in[31];
    const float* rh_b     = (const float*)d_in[32];

    char* wsb = (char*)d_ws;
    __bf16* tmp     = (__bf16*)(wsb + 0);                      // 16 MiB (proj partial A)
    __bf16* tmp2    = tmp + 8388608;                           // 16 MiB (proj partial B)
    __bf16* xb      = (__bf16*)(wsb + 33554432);               // 16 MiB bf16 residual stream
    __bf16* vT      = (__bf16*)(wsb + 67108864);               // 16 MiB  [b][h][d][s]
    __bf16* qkvB    = (__bf16*)(wsb + 83886080);               // region R1 (64 MiB): qkv / ff1 / states
    __bf16* ff1B    = qkvB;
    __bf16* statesB = qkvB;
    __bf16* obswB   = (__bf16*)(wsb + 83886080 + 8388608);
    __bf16* attnB   = (__bf16*)(wsb + 150994944);              // 16 MiB
    __bf16* wqkvB   = (__bf16*)(wsb + 167772160);
    __bf16* woB     = (__bf16*)(wsb + 177209344);
    __bf16* w1B     = (__bf16*)(wsb + 180355072);
    __bf16* w2B     = (__bf16*)(wsb + 192937984);
    __bf16* shwB    = (__bf16*)(wsb + 205520896);
    float*  ahwT    = (float*)(wsb + 207618048);

    cvt_f32_bf16<<<4608, 256, 0, stream>>>(Wqkv, wqkvB, 1179648);
    cvt_f32_bf16<<<1536, 256, 0, stream>>>(Wo, woB, 393216);
    cvt_f32_bf16<<<6144, 256, 0, stream>>>(W1, w1B, 1572864);
    cvt_f32_bf16<<<6144, 256, 0, stream>>>(W2, w2B, 1572864);
    cvt_f32_bf16<<<4096, 256, 0, stream>>>(states, statesB, 1048576);
    transpose_cvt<<<dim3(512, 8), 256, 0, stream>>>(obs_W, obswB, 256, 512);
    transpose_cvt<<<dim3(512, 8), 256, 0, stream>>>(sh_W, shwB, 512, 256);
    transpose_f32<<<dim3(36, 8), 256, 0, stream>>>(ah_W, ahwT, 512, 18);

    // embedding: se_raw = states @ obs_W[g] + obs_b[g]  (grouped, z=batch)
    gemm_bt<<<dim3(4, 4, 32), 256, 0, stream>>>(
        statesB, (size_t)512 * 256, obswB, (size_t)512 * 256, obs_b, 512,
        nullptr, tmp, (size_t)512 * 512, gi, 256, 256, 0, 512, 0, nullptr);
    embed_fin<<<4096, 256, 0, stream>>>(tmp, gi, actions, rtg, ts,
        obs_ln_g, obs_ln_b, act_emb, ret_W, ret_b, time_emb, game_emb, xb);

    for (int l = 0; l < 6; ++l) {
        // QKV (V third written transposed into vT)
        gemm_bt<<<dim3(12, 128, 1), 256, 0, stream>>>(
            xb, 0, wqkvB + (size_t)l * 1536 * 512, 0, bqkv + l * 1536, 0,
            nullptr, qkvB, 0, nullptr, 512, 512, 0, 1536, 0, vT);
        // attention
        attn_fwd_c<<<dim3(256, 4, 1), 256, 0, stream>>>(qkvB, vT, amask, attnB);
        // Wo projection, split-K=2 (z = K-half; bias on z=0; partials tmp/tmp2)
        gemm_bt<<<dim3(4, 128, 2), 256, 0, stream>>>(
            attnB, 0, woB + (size_t)l * 512 * 512, 0, bo + l * 512, 0,
            nullptr, tmp, 0, nullptr, 512, 256, 8388608, 512, 0, nullptr);
        ln_fuse2<<<4096, 256, 0, stream>>>(xb, tmp, tmp2, ln1_g + l * 512, ln1_b + l * 512, xb);
        // FF1 (relu): 256x256 8-wave phase-split kernel
        gemm256<<<dim3(8, 64), 512, 0, stream>>>(
            xb, w1B + (size_t)l * 2048 * 512, b1 + l * 2048, ff1B, 2048, 1);
        // FF2, split-K=2
        gemm_bt<<<dim3(4, 128, 2), 256, 0, stream>>>(
            ff1B, 0, w2B + (size_t)l * 512 * 2048, 0, b2 + l * 512, 0,
            nullptr, tmp, 0, nullptr, 2048, 1024, 8388608, 512, 0, nullptr);
        ln_fuse2<<<4096, 256, 0, stream>>>(xb, tmp, tmp2, ln2_g + l * 512, ln2_b + l * 512, xb);
    }

    // state head (grouped, writes d_out[0 : 32*512*256))
    gemm_bt<<<dim3(2, 4, 32), 256, 0, stream>>>(
        xb, (size_t)512 * 512, shwB, (size_t)256 * 512, sh_b, 256,
        (float*)d_out, nullptr, (size_t)512 * 256, gi, 512, 512, 0, 256, 0, nullptr);
    // action + return heads
    head_ar<<<4096, 256, 0, stream>>>(xb, gi, ahwT, ah_b, rh_W, rh_b,
        (float*)d_out + 4194304, (float*)d_out + 4489216);
}